// Round 1
// baseline (1111.379 us; speedup 1.0000x reference)
//
#include <hip/hip_runtime.h>
#include <stdint.h>

// Problem constants
#define K_CODES 8192
#define D 256
#define NROWS 16384      // 16 * 32 * 32
#define NELEM 4194304    // 16 * 256 * 32 * 32

// ws layout (bytes)
#define WS_DW     0                        // 8192*256 f32 = 8 MB
#define WS_COUNTS (8u*1024*1024)           // 8192 f32
#define WS_ENORM  (WS_COUNTS + 32u*1024)   // 8192 f32
#define WS_KEYS   (WS_ENORM + 32u*1024)    // 16384 u64
#define WS_PART   (WS_KEYS + 128u*1024)    // 256 f32

// out offsets (floats), concatenated return order
#define O_QST  0
#define O_LOSS 4194304
#define O_PERP 4194305
#define O_EMB  4194306
#define O_CS   6291458
#define O_EAVG 6299650

// ---------------------------------------------------------------------------
// e_norms[k] = sum_c emb[k][c]^2   (one wave per code)
__global__ __launch_bounds__(256) void enorm_kernel(const float* __restrict__ emb,
                                                    float* __restrict__ enorm) {
    const int w = threadIdx.x >> 6, lane = threadIdx.x & 63;
    const int k = blockIdx.x * 4 + w;
    const float4 v = *(const float4*)&emb[(size_t)k * D + (lane << 2)];
    float s = v.x * v.x + v.y * v.y + v.z * v.z + v.w * v.w;
#pragma unroll
    for (int off = 32; off; off >>= 1) s += __shfl_down(s, off, 64);
    if (lane == 0) enorm[k] = s;
}

// ---------------------------------------------------------------------------
// Distance GEMM + fused argmin.
// s[n][k] = enorm[k] - 2 * dot(x_n, e_k)   (|x|^2 constant per row, dropped)
// Tile: BM=128 rows x BN=128 codes x BK=32, 256 threads, 8x8 micro-tile.
// A-tile loads straight from x: channel dim IS the k dim (x is channel-major),
// so rows n0..n0+127 (same batch b, consecutive hw) are coalesced along hw.
#define BM 128
#define BN 128
#define BK 32

__global__ __launch_bounds__(256) void dist_kernel(const float* __restrict__ x,
                                                   const float* __restrict__ emb,
                                                   const float* __restrict__ enorm,
                                                   unsigned long long* __restrict__ keys) {
    __shared__ __align__(16) float As[BK][BM];       // k-major
    __shared__ __align__(16) float Bs[BK][BN + 4];   // pad 4: aligned float4 rows, <=4-way write conflicts

    const int tid = threadIdx.x;
    const int tx = tid & 15, ty = tid >> 4;
    const int c0 = blockIdx.x * BN;   // code block
    const int n0 = blockIdx.y * BM;   // row block
    const int b = n0 >> 10;           // batch (128 | 1024, so one b per block)
    const int hw0 = n0 & 1023;

    float acc[8][8];
#pragma unroll
    for (int i = 0; i < 8; i++)
#pragma unroll
        for (int j = 0; j < 8; j++) acc[i][j] = 0.f;

    const int ai = tid >> 5;    // 0..7  (k row within pass)
    const int aj = tid & 31;    // float4 col
    const int bcol = tid >> 3;  // 0..31 (code within pass)
    const int bd = tid & 7;     // float4 along d

    for (int kt = 0; kt < D / BK; ++kt) {
        const int kc = kt * BK;
        __syncthreads();
#pragma unroll
        for (int p = 0; p < 4; ++p) {
            const int i = p * 8 + ai;
            const float4 v = *(const float4*)&x[((size_t)(b * 256 + kc + i) << 10) + hw0 + (aj << 2)];
            *(float4*)&As[i][aj << 2] = v;
        }
#pragma unroll
        for (int p = 0; p < 4; ++p) {
            const int col = p * 32 + bcol;
            const float4 v = *(const float4*)&emb[(size_t)(c0 + col) * D + kc + (bd << 2)];
            Bs[bd * 4 + 0][col] = v.x;
            Bs[bd * 4 + 1][col] = v.y;
            Bs[bd * 4 + 2][col] = v.z;
            Bs[bd * 4 + 3][col] = v.w;
        }
        __syncthreads();
#pragma unroll
        for (int k = 0; k < BK; ++k) {
            float a[8], bv[8];
            *(float4*)&a[0] = *(const float4*)&As[k][ty * 8];
            *(float4*)&a[4] = *(const float4*)&As[k][ty * 8 + 4];
            *(float4*)&bv[0] = *(const float4*)&Bs[k][tx * 8];
            *(float4*)&bv[4] = *(const float4*)&Bs[k][tx * 8 + 4];
#pragma unroll
            for (int i = 0; i < 8; i++)
#pragma unroll
                for (int j = 0; j < 8; j++) acc[i][j] = fmaf(a[i], bv[j], acc[i][j]);
        }
    }

    // Epilogue: per-row min over this block's 128 codes -> global atomicMin on
    // orderable (dist, idx) u64 key (ties -> lowest code index, as numpy argmin).
    float en[8];
#pragma unroll
    for (int j = 0; j < 8; j++) en[j] = enorm[c0 + tx * 8 + j];

#pragma unroll
    for (int i = 0; i < 8; i++) {
        float bv = fmaf(-2.f, acc[i][0], en[0]);
        int bi = c0 + tx * 8;
#pragma unroll
        for (int j = 1; j < 8; j++) {
            const float s = fmaf(-2.f, acc[i][j], en[j]);
            const int ci = c0 + tx * 8 + j;
            if (s < bv) { bv = s; bi = ci; }  // strict <: earlier (lower) idx wins ties
        }
#pragma unroll
        for (int m = 1; m < 16; m <<= 1) {
            const float ov = __shfl_xor(bv, m, 64);
            const int oi = __shfl_xor(bi, m, 64);
            if (ov < bv || (ov == bv && oi < bi)) { bv = ov; bi = oi; }
        }
        if (tx == 0) {
            unsigned int u = __float_as_uint(bv);
            u = (u & 0x80000000u) ? ~u : (u | 0x80000000u);
            const unsigned long long key = ((unsigned long long)u << 32) | (unsigned int)bi;
            atomicMin(&keys[n0 + ty * 8 + i], key);
        }
    }
}

// ---------------------------------------------------------------------------
// counts[k] += 1 per row; dw[k][:] += flat[n][:]  (atomics; avg 2 rows/code)
// Block = (b, 64-wide hw tile); coalesced x reads (consecutive hw per wave).
__global__ __launch_bounds__(256) void scatter_kernel(const float* __restrict__ x,
                                                      const unsigned long long* __restrict__ keys,
                                                      float* __restrict__ dw,
                                                      float* __restrict__ counts) {
    const int blk = blockIdx.x;
    const int b = blk >> 4;
    const int hw0 = (blk & 15) << 6;
    const int l = threadIdx.x & 63;
    const int cq = threadIdx.x >> 6;
    const int hw = hw0 + l;
    const int n = (b << 10) + hw;
    const int code = (int)(keys[n] & 0xFFFFFFFFull);
    if (threadIdx.x < 64) atomicAdd(&counts[code], 1.0f);
    float* dwrow = dw + (size_t)code * D;
    const float* xb = x + (((size_t)b * 256) << 10) + hw;
#pragma unroll 4
    for (int c = cq; c < D; c += 4) {
        atomicAdd(&dwrow[c], xb[(size_t)c << 10]);
    }
}

// ---------------------------------------------------------------------------
// EMA buffer updates: new_embed_avg, new_cluster_size, new_embedding
__global__ __launch_bounds__(256) void ema_kernel(const float* __restrict__ embed_avg,
                                                  const float* __restrict__ cluster_size,
                                                  const float* __restrict__ dw,
                                                  const float* __restrict__ counts,
                                                  float* __restrict__ out) {
    const int k = blockIdx.x, c = threadIdx.x;
    const size_t i = (size_t)k * D + c;
    const float na = embed_avg[i] * 0.99f + 0.01f * dw[i];
    const float ncs = cluster_size[k] * 0.99f + 0.01f * counts[k];
    out[O_EAVG + i] = na;
    out[O_EMB + i] = na / fmaxf(ncs, 1e-5f);
    if (c == 0) out[O_CS + k] = ncs;
}

// ---------------------------------------------------------------------------
// quantized_st (= x + (q - x), same fp ops as ref) and loss partial sums
__global__ __launch_bounds__(256) void quant_loss_kernel(const float* __restrict__ x,
                                                         const float* __restrict__ emb,
                                                         const unsigned long long* __restrict__ keys,
                                                         float* __restrict__ out,
                                                         float* __restrict__ partials) {
    const int blk = blockIdx.x;
    const int b = blk >> 4;
    const int hw0 = (blk & 15) << 6;
    const int l = threadIdx.x & 63;
    const int cq = threadIdx.x >> 6;
    const int hw = hw0 + l;
    const int n = (b << 10) + hw;
    const int code = (int)(keys[n] & 0xFFFFFFFFull);
    const float* erow = emb + (size_t)code * D;
    const float* xb = x + (((size_t)b * 256) << 10) + hw;
    float* ob = out + O_QST + (((size_t)b * 256) << 10) + hw;
    float lsum = 0.f;
#pragma unroll 4
    for (int c = cq; c < D; c += 4) {
        const float xv = xb[(size_t)c << 10];
        const float ev = erow[c];
        ob[(size_t)c << 10] = xv + (ev - xv);
        const float d = xv - ev;
        lsum = fmaf(d, d, lsum);
    }
    __shared__ float sm[4];
    const int lane = threadIdx.x & 63, w = threadIdx.x >> 6;
#pragma unroll
    for (int off = 32; off; off >>= 1) lsum += __shfl_down(lsum, off, 64);
    if (lane == 0) sm[w] = lsum;
    __syncthreads();
    if (threadIdx.x == 0) partials[blockIdx.x] = sm[0] + sm[1] + sm[2] + sm[3];
}

// ---------------------------------------------------------------------------
// Final scalars: loss, perplexity
__global__ __launch_bounds__(256) void final_kernel(const float* __restrict__ partials,
                                                    const float* __restrict__ counts,
                                                    float* __restrict__ out) {
    const int tid = threadIdx.x;
    const int lane = tid & 63, w = tid >> 6;
    __shared__ float sm[8];
    float t = partials[tid];
#pragma unroll
    for (int off = 32; off; off >>= 1) t += __shfl_down(t, off, 64);
    float ps = 0.f;
    for (int i = tid; i < K_CODES; i += 256) {
        const float p = counts[i] * (1.0f / 16384.0f);
        ps += p * logf(p + 1e-10f);
    }
#pragma unroll
    for (int off = 32; off; off >>= 1) ps += __shfl_down(ps, off, 64);
    if (lane == 0) { sm[w] = t; sm[4 + w] = ps; }
    __syncthreads();
    if (tid == 0) {
        const float total = sm[0] + sm[1] + sm[2] + sm[3];
        out[O_LOSS] = 0.25f * (total / 4194304.0f);
        const float P = sm[4] + sm[5] + sm[6] + sm[7];
        out[O_PERP] = expf(-P);
    }
}

// ---------------------------------------------------------------------------
extern "C" void kernel_launch(void* const* d_in, const int* in_sizes, int n_in,
                              void* d_out, int out_size, void* d_ws, size_t ws_size,
                              hipStream_t stream) {
    const float* x            = (const float*)d_in[0];
    const float* emb          = (const float*)d_in[1];
    const float* cluster_size = (const float*)d_in[2];
    const float* embed_avg    = (const float*)d_in[3];
    float* out = (float*)d_out;
    char* ws = (char*)d_ws;

    float* dw = (float*)(ws + WS_DW);
    float* counts = (float*)(ws + WS_COUNTS);
    float* enorm = (float*)(ws + WS_ENORM);
    unsigned long long* keys = (unsigned long long*)(ws + WS_KEYS);
    float* partials = (float*)(ws + WS_PART);

    // zero dw+counts (contiguous), set argmin keys to +inf-equivalent
    hipMemsetAsync(ws + WS_DW, 0, (8u * 1024 * 1024) + 32u * 1024, stream);
    hipMemsetAsync(ws + WS_KEYS, 0xFF, NROWS * sizeof(unsigned long long), stream);

    enorm_kernel<<<K_CODES / 4, 256, 0, stream>>>(emb, enorm);
    dist_kernel<<<dim3(K_CODES / BN, NROWS / BM), 256, 0, stream>>>(x, emb, enorm, keys);
    scatter_kernel<<<256, 256, 0, stream>>>(x, keys, dw, counts);
    ema_kernel<<<K_CODES, 256, 0, stream>>>(embed_avg, cluster_size, dw, counts, out);
    quant_loss_kernel<<<256, 256, 0, stream>>>(x, emb, keys, out, partials);
    final_kernel<<<1, 256, 0, stream>>>(partials, counts, out);
}

// Round 2
// 731.040 us; speedup vs baseline: 1.5203x; 1.5203x over previous
//
#include <hip/hip_runtime.h>
#include <stdint.h>

// Problem constants
#define K_CODES 8192
#define D 256
#define NROWS 16384      // 16 * 32 * 32
#define NELEM 4194304    // 16 * 256 * 32 * 32

// ws layout (bytes)
#define WS_DW     0u                        // 8192*256 f32 = 8 MB
#define WS_COUNTS 0x800000u                 // 8192 f32 (contiguous after DW for one memset)
#define WS_ENORM  0x808000u                 // 8192 f32
#define WS_KEYS   0x810000u                 // 16384 u64 = 128 KB
#define WS_PART   0x830000u                 // 256 f32
#define WS_XHI    0x840000u                 // 16384*256 bf16 = 8 MB
#define WS_XLO    (WS_XHI + 0x800000u)      // 8 MB
#define WS_EHI    (WS_XLO + 0x800000u)      // 8192*256 bf16 = 4 MB
#define WS_ELO    (WS_EHI + 0x400000u)      // 4 MB

// out offsets (floats), concatenated return order
#define O_QST  0
#define O_LOSS 4194304
#define O_PERP 4194305
#define O_EMB  4194306
#define O_CS   6291458
#define O_EAVG 6299650

typedef unsigned short u16;
typedef __attribute__((ext_vector_type(8))) short bf16x8;
typedef __attribute__((ext_vector_type(4))) float f32x4;

// bf16 round-to-nearest-even split helpers
__device__ __forceinline__ u16 f2bf(float f) {
    uint32_t u = __float_as_uint(f);
    u += 0x7FFFu + ((u >> 16) & 1u);
    return (u16)(u >> 16);
}
__device__ __forceinline__ float bf2f(u16 h) {
    return __uint_as_float(((uint32_t)h) << 16);
}

__device__ __forceinline__ void glds16(const u16* g, u16* lds_base) {
    __builtin_amdgcn_global_load_lds(
        (const __attribute__((address_space(1))) uint32_t*)g,
        (__attribute__((address_space(3))) uint32_t*)lds_base, 16, 0, 0);
}

// ---------------------------------------------------------------------------
// Split emb rows into bf16 hi/lo planes (same [k][c] layout) + row norms.
__global__ __launch_bounds__(256) void prep_emb_kernel(const float* __restrict__ emb,
                                                       u16* __restrict__ eh,
                                                       u16* __restrict__ el,
                                                       float* __restrict__ enorm) {
    const int k = blockIdx.x, t = threadIdx.x;
    const size_t i = (size_t)k * D + t;
    const float v = emb[i];
    const u16 h = f2bf(v);
    const float r = v - bf2f(h);  // exact
    eh[i] = h;
    el[i] = f2bf(r);
    float s = v * v;
#pragma unroll
    for (int off = 32; off; off >>= 1) s += __shfl_down(s, off, 64);
    __shared__ float sm[4];
    if ((t & 63) == 0) sm[t >> 6] = s;
    __syncthreads();
    if (t == 0) enorm[k] = sm[0] + sm[1] + sm[2] + sm[3];
}

// ---------------------------------------------------------------------------
// Split + transpose x: [b][c][hw] f32 -> xhi/xlo [n = b*1024+hw][c] bf16.
// 64c x 64hw tile per block through LDS (row stride 72 ushorts: 16B-aligned
// rows, ~2-way max bank aliasing on both phases).
__global__ __launch_bounds__(256) void prep_x_kernel(const float* __restrict__ x,
                                                     u16* __restrict__ xhi,
                                                     u16* __restrict__ xlo) {
    __shared__ u16 Lh[64][72];
    __shared__ u16 Ll[64][72];
    const int hw0 = blockIdx.x << 6;
    const int c0 = blockIdx.y << 6;
    const int b = blockIdx.z;
    const int t = threadIdx.x, l = t & 63, w = t >> 6;
#pragma unroll
    for (int i = 0; i < 16; ++i) {
        const int cl = w * 16 + i;
        const float v = x[(((size_t)(b * 256 + c0 + cl)) << 10) + hw0 + l];
        const u16 h = f2bf(v);
        Lh[l][cl] = h;
        Ll[l][cl] = f2bf(v - bf2f(h));
    }
    __syncthreads();
    const int r = t >> 2, cs = t & 3;
    const size_t n = (((size_t)b) << 10) + hw0 + r;
    const size_t o = n * D + c0 + cs * 16;
    *(uint4*)&xhi[o]     = *(const uint4*)&Lh[r][cs * 16];
    *(uint4*)&xhi[o + 8] = *(const uint4*)&Lh[r][cs * 16 + 8];
    *(uint4*)&xlo[o]     = *(const uint4*)&Ll[r][cs * 16];
    *(uint4*)&xlo[o + 8] = *(const uint4*)&Ll[r][cs * 16 + 8];
}

// ---------------------------------------------------------------------------
// Distance GEMM via bf16 hi/lo-split MFMA + fused argmin.
// s[n][k] = enorm[k] - 2*dot(x_n, e_k); dot = hh + hl + lh (ll dropped,
// rel err ~2^-17). m97 structure: 128x128 tile, BK=32, 4 waves, each wave a
// 4x4 grid of 16x16x32 MFMA tiles; global_load_lds width-16 staging.
#define BM 128
#define BN 128
#define BK 32

__global__ __launch_bounds__(256) void dist_kernel(const u16* __restrict__ xhi,
                                                   const u16* __restrict__ xlo,
                                                   const u16* __restrict__ ehi,
                                                   const u16* __restrict__ elo,
                                                   const float* __restrict__ enorm,
                                                   unsigned long long* __restrict__ keys) {
    __shared__ __align__(16) u16 Ah[BM * BK];
    __shared__ __align__(16) u16 Al[BM * BK];
    __shared__ __align__(16) u16 Bh[BN * BK];
    __shared__ __align__(16) u16 Bl[BN * BK];

    const int tid = threadIdx.x;
    const int l = tid & 63, w = tid >> 6;
    const int wr = w >> 1, wc = w & 1;       // wave's 64x64 quadrant
    const int c0 = blockIdx.x * BN;          // code block
    const int n0 = blockIdx.y * BM;          // row block
    const int md = l & 15, quad = l >> 4;

    f32x4 acc[4][4];
#pragma unroll
    for (int i = 0; i < 4; ++i)
#pragma unroll
        for (int j = 0; j < 4; ++j) acc[i][j] = (f32x4)0.f;

    for (int kt = 0; kt < D / BK; ++kt) {
        const int kc = kt * BK;
        __syncthreads();
#pragma unroll
        for (int c = 0; c < 2; ++c) {
            // chunk = w*128 + c*64 + l; LDS dest = chunk*16B (HW adds l*16)
            const int chunk = w * 128 + c * 64 + l;
            const int row = chunk >> 2, seg = chunk & 3;
            const size_t ga = (size_t)(n0 + row) * D + kc + seg * 8;
            const size_t gb = (size_t)(c0 + row) * D + kc + seg * 8;
            const int base = w * 1024 + c * 512;  // ushort offset, wave-uniform
            glds16(xhi + ga, &Ah[base]);
            glds16(xlo + ga, &Al[base]);
            glds16(ehi + gb, &Bh[base]);
            glds16(elo + gb, &Bl[base]);
        }
        __syncthreads();

        bf16x8 ah[4], al4[4], bh4[4], bl4[4];
#pragma unroll
        for (int i = 0; i < 4; ++i) {
            const int ra = (wr * 64 + i * 16 + md) * BK + quad * 8;
            const int rb = (wc * 64 + i * 16 + md) * BK + quad * 8;
            ah[i]  = *(const bf16x8*)&Ah[ra];
            al4[i] = *(const bf16x8*)&Al[ra];
            bh4[i] = *(const bf16x8*)&Bh[rb];
            bl4[i] = *(const bf16x8*)&Bl[rb];
        }
#pragma unroll
        for (int i = 0; i < 4; ++i)
#pragma unroll
            for (int j = 0; j < 4; ++j) {
                acc[i][j] = __builtin_amdgcn_mfma_f32_16x16x32_bf16(ah[i],  bh4[j], acc[i][j], 0, 0, 0);
                acc[i][j] = __builtin_amdgcn_mfma_f32_16x16x32_bf16(ah[i],  bl4[j], acc[i][j], 0, 0, 0);
                acc[i][j] = __builtin_amdgcn_mfma_f32_16x16x32_bf16(al4[i], bh4[j], acc[i][j], 0, 0, 0);
            }
    }

    // Epilogue: per-row argmin over this wave's 64 codes, then global
    // atomicMin on orderable (dist,idx) u64 key (ties -> lowest idx).
    float ec[4];
#pragma unroll
    for (int j = 0; j < 4; ++j) ec[j] = enorm[c0 + wc * 64 + j * 16 + md];

#pragma unroll
    for (int i = 0; i < 4; ++i) {
#pragma unroll
        for (int r = 0; r < 4; ++r) {
            float bv = fmaf(-2.f, acc[i][0][r], ec[0]);
            int bi = c0 + wc * 64 + md;
#pragma unroll
            for (int j = 1; j < 4; ++j) {
                const float s = fmaf(-2.f, acc[i][j][r], ec[j]);
                const int ci = c0 + wc * 64 + j * 16 + md;
                if (s < bv) { bv = s; bi = ci; }  // ci>bi within thread: strict ok
            }
#pragma unroll
            for (int m = 1; m < 16; m <<= 1) {
                const float ov = __shfl_xor(bv, m, 64);
                const int oi = __shfl_xor(bi, m, 64);
                if (ov < bv || (ov == bv && oi < bi)) { bv = ov; bi = oi; }
            }
            if (md == 0) {
                unsigned int u = __float_as_uint(bv);
                u = (u & 0x80000000u) ? ~u : (u | 0x80000000u);
                const unsigned long long key = ((unsigned long long)u << 32) | (unsigned int)bi;
                atomicMin(&keys[n0 + wr * 64 + i * 16 + quad * 4 + r], key);
            }
        }
    }
}

// ---------------------------------------------------------------------------
// counts[k] += 1 per row; dw[k][:] += flat[n][:]  (atomics; avg 2 rows/code)
__global__ __launch_bounds__(256) void scatter_kernel(const float* __restrict__ x,
                                                      const unsigned long long* __restrict__ keys,
                                                      float* __restrict__ dw,
                                                      float* __restrict__ counts) {
    const int blk = blockIdx.x;
    const int b = blk >> 4;
    const int hw0 = (blk & 15) << 6;
    const int l = threadIdx.x & 63;
    const int cq = threadIdx.x >> 6;
    const int hw = hw0 + l;
    const int n = (b << 10) + hw;
    const int code = (int)(keys[n] & 0xFFFFFFFFull);
    if (threadIdx.x < 64) atomicAdd(&counts[code], 1.0f);
    float* dwrow = dw + (size_t)code * D;
    const float* xb = x + (((size_t)b * 256) << 10) + hw;
#pragma unroll 4
    for (int c = cq; c < D; c += 4) {
        atomicAdd(&dwrow[c], xb[(size_t)c << 10]);
    }
}

// ---------------------------------------------------------------------------
// EMA buffer updates: new_embed_avg, new_cluster_size, new_embedding
__global__ __launch_bounds__(256) void ema_kernel(const float* __restrict__ embed_avg,
                                                  const float* __restrict__ cluster_size,
                                                  const float* __restrict__ dw,
                                                  const float* __restrict__ counts,
                                                  float* __restrict__ out) {
    const int k = blockIdx.x, c = threadIdx.x;
    const size_t i = (size_t)k * D + c;
    const float na = embed_avg[i] * 0.99f + 0.01f * dw[i];
    const float ncs = cluster_size[k] * 0.99f + 0.01f * counts[k];
    out[O_EAVG + i] = na;
    out[O_EMB + i] = na / fmaxf(ncs, 1e-5f);
    if (c == 0) out[O_CS + k] = ncs;
}

// ---------------------------------------------------------------------------
// quantized_st (= x + (q - x), same fp ops as ref) and loss partial sums
__global__ __launch_bounds__(256) void quant_loss_kernel(const float* __restrict__ x,
                                                         const float* __restrict__ emb,
                                                         const unsigned long long* __restrict__ keys,
                                                         float* __restrict__ out,
                                                         float* __restrict__ partials) {
    const int blk = blockIdx.x;
    const int b = blk >> 4;
    const int hw0 = (blk & 15) << 6;
    const int l = threadIdx.x & 63;
    const int cq = threadIdx.x >> 6;
    const int hw = hw0 + l;
    const int n = (b << 10) + hw;
    const int code = (int)(keys[n] & 0xFFFFFFFFull);
    const float* erow = emb + (size_t)code * D;
    const float* xb = x + (((size_t)b * 256) << 10) + hw;
    float* ob = out + O_QST + (((size_t)b * 256) << 10) + hw;
    float lsum = 0.f;
#pragma unroll 4
    for (int c = cq; c < D; c += 4) {
        const float xv = xb[(size_t)c << 10];
        const float ev = erow[c];
        ob[(size_t)c << 10] = xv + (ev - xv);
        const float d = xv - ev;
        lsum = fmaf(d, d, lsum);
    }
    __shared__ float sm[4];
    const int lane = threadIdx.x & 63, wv = threadIdx.x >> 6;
#pragma unroll
    for (int off = 32; off; off >>= 1) lsum += __shfl_down(lsum, off, 64);
    if (lane == 0) sm[wv] = lsum;
    __syncthreads();
    if (threadIdx.x == 0) partials[blockIdx.x] = sm[0] + sm[1] + sm[2] + sm[3];
}

// ---------------------------------------------------------------------------
// Final scalars: loss, perplexity
__global__ __launch_bounds__(256) void final_kernel(const float* __restrict__ partials,
                                                    const float* __restrict__ counts,
                                                    float* __restrict__ out) {
    const int tid = threadIdx.x;
    const int lane = tid & 63, w = tid >> 6;
    __shared__ float sm[8];
    float t = partials[tid];
#pragma unroll
    for (int off = 32; off; off >>= 1) t += __shfl_down(t, off, 64);
    float ps = 0.f;
    for (int i = tid; i < K_CODES; i += 256) {
        const float p = counts[i] * (1.0f / 16384.0f);
        ps += p * logf(p + 1e-10f);
    }
#pragma unroll
    for (int off = 32; off; off >>= 1) ps += __shfl_down(ps, off, 64);
    if (lane == 0) { sm[w] = t; sm[4 + w] = ps; }
    __syncthreads();
    if (tid == 0) {
        const float total = sm[0] + sm[1] + sm[2] + sm[3];
        out[O_LOSS] = 0.25f * (total / 4194304.0f);
        const float P = sm[4] + sm[5] + sm[6] + sm[7];
        out[O_PERP] = expf(-P);
    }
}

// ---------------------------------------------------------------------------
extern "C" void kernel_launch(void* const* d_in, const int* in_sizes, int n_in,
                              void* d_out, int out_size, void* d_ws, size_t ws_size,
                              hipStream_t stream) {
    const float* x            = (const float*)d_in[0];
    const float* emb          = (const float*)d_in[1];
    const float* cluster_size = (const float*)d_in[2];
    const float* embed_avg    = (const float*)d_in[3];
    float* out = (float*)d_out;
    char* ws = (char*)d_ws;

    float* dw = (float*)(ws + WS_DW);
    float* counts = (float*)(ws + WS_COUNTS);
    float* enorm = (float*)(ws + WS_ENORM);
    unsigned long long* keys = (unsigned long long*)(ws + WS_KEYS);
    float* partials = (float*)(ws + WS_PART);
    u16* xhi = (u16*)(ws + WS_XHI);
    u16* xlo = (u16*)(ws + WS_XLO);
    u16* ehi = (u16*)(ws + WS_EHI);
    u16* elo = (u16*)(ws + WS_ELO);

    // zero dw+counts (contiguous), set argmin keys to +inf-equivalent
    hipMemsetAsync(ws + WS_DW, 0, 0x800000u + 0x8000u, stream);
    hipMemsetAsync(ws + WS_KEYS, 0xFF, NROWS * sizeof(unsigned long long), stream);

    prep_emb_kernel<<<K_CODES, 256, 0, stream>>>(emb, ehi, elo, enorm);
    prep_x_kernel<<<dim3(16, 4, 16), 256, 0, stream>>>(x, xhi, xlo);
    dist_kernel<<<dim3(K_CODES / BN, NROWS / BM), 256, 0, stream>>>(xhi, xlo, ehi, elo, enorm, keys);
    scatter_kernel<<<256, 256, 0, stream>>>(x, keys, dw, counts);
    ema_kernel<<<K_CODES, 256, 0, stream>>>(embed_avg, cluster_size, dw, counts, out);
    quant_loss_kernel<<<256, 256, 0, stream>>>(x, emb, keys, out, partials);
    final_kernel<<<1, 256, 0, stream>>>(partials, counts, out);
}

// Round 3
// 358.067 us; speedup vs baseline: 3.1038x; 2.0416x over previous
//
#include <hip/hip_runtime.h>
#include <stdint.h>

// Problem constants
#define K_CODES 8192
#define D 256
#define NROWS 16384      // 16 * 32 * 32
#define NELEM 4194304    // 16 * 256 * 32 * 32

// ws layout (bytes)
#define WS_ENORM   0x00000u                 // 8192 f32 = 32 KB
#define WS_KEYS    0x08000u                 // 16384 u64 = 128 KB
#define WS_ICOUNTS 0x28000u                 // 8192 i32 = 32 KB
#define WS_CURSOR  0x30000u                 // 8192 i32 = 32 KB
#define WS_BASE    0x38000u                 // 8192 i32 = 32 KB
#define WS_ROWLIST 0x40000u                 // 16384 i32 = 64 KB
#define WS_PART    0x50000u                 // 256 f32
#define WS_XHI     0x60000u                 // 16384*256 bf16 = 8 MB
#define WS_XLO     (WS_XHI + 0x800000u)     // 8 MB
#define WS_EHI     (WS_XLO + 0x800000u)     // 4 MB
#define WS_ELO     (WS_EHI + 0x400000u)     // 4 MB

// out offsets (floats), concatenated return order
#define O_QST  0
#define O_LOSS 4194304
#define O_PERP 4194305
#define O_EMB  4194306
#define O_CS   6291458
#define O_EAVG 6299650

typedef unsigned short u16;
typedef __attribute__((ext_vector_type(8))) short bf16x8;
typedef __attribute__((ext_vector_type(4))) float f32x4;

// bf16 round-to-nearest-even split helpers
__device__ __forceinline__ u16 f2bf(float f) {
    uint32_t u = __float_as_uint(f);
    u += 0x7FFFu + ((u >> 16) & 1u);
    return (u16)(u >> 16);
}
__device__ __forceinline__ float bf2f(u16 h) {
    return __uint_as_float(((uint32_t)h) << 16);
}

__device__ __forceinline__ void glds16(const u16* g, u16* lds_base) {
    __builtin_amdgcn_global_load_lds(
        (const __attribute__((address_space(1))) uint32_t*)g,
        (__attribute__((address_space(3))) uint32_t*)lds_base, 16, 0, 0);
}

// ---------------------------------------------------------------------------
// Split emb rows into bf16 hi/lo planes (same [k][c] layout) + row norms.
__global__ __launch_bounds__(256) void prep_emb_kernel(const float* __restrict__ emb,
                                                       u16* __restrict__ eh,
                                                       u16* __restrict__ el,
                                                       float* __restrict__ enorm) {
    const int k = blockIdx.x, t = threadIdx.x;
    const size_t i = (size_t)k * D + t;
    const float v = emb[i];
    const u16 h = f2bf(v);
    const float r = v - bf2f(h);  // exact
    eh[i] = h;
    el[i] = f2bf(r);
    float s = v * v;
#pragma unroll
    for (int off = 32; off; off >>= 1) s += __shfl_down(s, off, 64);
    __shared__ float sm[4];
    if ((t & 63) == 0) sm[t >> 6] = s;
    __syncthreads();
    if (t == 0) enorm[k] = sm[0] + sm[1] + sm[2] + sm[3];
}

// ---------------------------------------------------------------------------
// Split + transpose x: [b][c][hw] f32 -> xhi/xlo [n = b*1024+hw][c] bf16.
__global__ __launch_bounds__(256) void prep_x_kernel(const float* __restrict__ x,
                                                     u16* __restrict__ xhi,
                                                     u16* __restrict__ xlo) {
    __shared__ u16 Lh[64][72];
    __shared__ u16 Ll[64][72];
    const int hw0 = blockIdx.x << 6;
    const int c0 = blockIdx.y << 6;
    const int b = blockIdx.z;
    const int t = threadIdx.x, l = t & 63, w = t >> 6;
#pragma unroll
    for (int i = 0; i < 16; ++i) {
        const int cl = w * 16 + i;
        const float v = x[(((size_t)(b * 256 + c0 + cl)) << 10) + hw0 + l];
        const u16 h = f2bf(v);
        Lh[l][cl] = h;
        Ll[l][cl] = f2bf(v - bf2f(h));
    }
    __syncthreads();
    const int r = t >> 2, cs = t & 3;
    const size_t n = (((size_t)b) << 10) + hw0 + r;
    const size_t o = n * D + c0 + cs * 16;
    *(uint4*)&xhi[o]     = *(const uint4*)&Lh[r][cs * 16];
    *(uint4*)&xhi[o + 8] = *(const uint4*)&Lh[r][cs * 16 + 8];
    *(uint4*)&xlo[o]     = *(const uint4*)&Ll[r][cs * 16];
    *(uint4*)&xlo[o + 8] = *(const uint4*)&Ll[r][cs * 16 + 8];
}

// ---------------------------------------------------------------------------
// Distance GEMM via bf16 hi/lo-split MFMA + fused argmin.
// Grid (8 slices, 128 row-blocks); each block loops 8 code-tiles of 128 codes
// (ct) x 8 k-tiles (kt): 64 staging iterations, single epilogue.
// LDS seg index XOR-swizzled so ds_read_b128 frag reads are 2-way (free):
//   slot s holds global seg g = (s - (row>>1)) & 3.
#define BM 128
#define BN 128
#define BK 32
#define SLICES 8
#define CT_PER 8

__global__ __launch_bounds__(256) void dist_kernel(const u16* __restrict__ xhi,
                                                   const u16* __restrict__ xlo,
                                                   const u16* __restrict__ ehi,
                                                   const u16* __restrict__ elo,
                                                   const float* __restrict__ enorm,
                                                   unsigned long long* __restrict__ keys) {
    __shared__ __align__(16) u16 Ah[BM * BK];
    __shared__ __align__(16) u16 Al[BM * BK];
    __shared__ __align__(16) u16 Bh[BN * BK];
    __shared__ __align__(16) u16 Bl[BN * BK];

    const int tid = threadIdx.x;
    const int l = tid & 63, w = tid >> 6;
    const int wr = w >> 1, wc = w & 1;       // wave's 64x64 quadrant
    const int slice = blockIdx.x;            // 0..7 (flat%8 -> per-XCD B locality)
    const int n0 = blockIdx.y * BM;          // row block
    const int md = l & 15, quad = l >> 4;

    // staging slot constants: plane slots c = p*256 + w*64 + l  (p=0,1)
    const int c0s = w * 64 + l;
    const int row0 = c0s >> 2, s0 = c0s & 3;
    const int g0 = (s0 - ((row0 >> 1) & 3)) & 3;
    const int c1s = 256 + w * 64 + l;
    const int row1 = c1s >> 2, s1 = c1s & 3;
    const int g1 = (s1 - ((row1 >> 1) & 3)) & 3;
    const int ldsb0 = w * 512;               // u16 index of wave's p=0 dest
    const int ldsb1 = 2048 + w * 512;
    const size_t aoff0 = (size_t)(n0 + row0) * D + g0 * 8;
    const size_t aoff1 = (size_t)(n0 + row1) * D + g1 * 8;

    // frag-read swizzled seg (row>>1 mod 4 == md>>1 mod 4 for our rows)
    const int sA = (quad + ((md >> 1) & 3)) & 3;

    float rbv[4][4];
    int rbi[4][4];
#pragma unroll
    for (int i = 0; i < 4; ++i)
#pragma unroll
        for (int r = 0; r < 4; ++r) { rbv[i][r] = 1e30f; rbi[i][r] = 0; }

    for (int ct = 0; ct < CT_PER; ++ct) {
        const int cbase = (slice * CT_PER + ct) * BN;
        const size_t boff0 = (size_t)(cbase + row0) * D + g0 * 8;
        const size_t boff1 = (size_t)(cbase + row1) * D + g1 * 8;

        f32x4 acc[4][4];
#pragma unroll
        for (int i = 0; i < 4; ++i)
#pragma unroll
            for (int j = 0; j < 4; ++j) acc[i][j] = (f32x4)0.f;

        for (int kt = 0; kt < D / BK; ++kt) {
            const int kc = kt * BK;
            __syncthreads();
            glds16(xhi + aoff0 + kc, &Ah[ldsb0]);
            glds16(xhi + aoff1 + kc, &Ah[ldsb1]);
            glds16(xlo + aoff0 + kc, &Al[ldsb0]);
            glds16(xlo + aoff1 + kc, &Al[ldsb1]);
            glds16(ehi + boff0 + kc, &Bh[ldsb0]);
            glds16(ehi + boff1 + kc, &Bh[ldsb1]);
            glds16(elo + boff0 + kc, &Bl[ldsb0]);
            glds16(elo + boff1 + kc, &Bl[ldsb1]);
            __syncthreads();

            bf16x8 ah[4], al4[4], bh4[4], bl4[4];
#pragma unroll
            for (int i = 0; i < 4; ++i) {
                const int ra = (wr * 64 + i * 16 + md) * BK + sA * 8;
                const int rb = (wc * 64 + i * 16 + md) * BK + sA * 8;
                ah[i]  = *(const bf16x8*)&Ah[ra];
                al4[i] = *(const bf16x8*)&Al[ra];
                bh4[i] = *(const bf16x8*)&Bh[rb];
                bl4[i] = *(const bf16x8*)&Bl[rb];
            }
#pragma unroll
            for (int i = 0; i < 4; ++i)
#pragma unroll
                for (int j = 0; j < 4; ++j) {
                    acc[i][j] = __builtin_amdgcn_mfma_f32_16x16x32_bf16(ah[i],  bh4[j], acc[i][j], 0, 0, 0);
                    acc[i][j] = __builtin_amdgcn_mfma_f32_16x16x32_bf16(ah[i],  bl4[j], acc[i][j], 0, 0, 0);
                    acc[i][j] = __builtin_amdgcn_mfma_f32_16x16x32_bf16(al4[i], bh4[j], acc[i][j], 0, 0, 0);
                }
        }

        // merge this ct's 128 codes into per-lane running best
        float ec[4];
#pragma unroll
        for (int j = 0; j < 4; ++j) ec[j] = enorm[cbase + wc * 64 + j * 16 + md];
#pragma unroll
        for (int i = 0; i < 4; ++i)
#pragma unroll
            for (int r = 0; r < 4; ++r)
#pragma unroll
                for (int j = 0; j < 4; ++j) {
                    const float s = fmaf(-2.f, acc[i][j][r], ec[j]);
                    const int ci = cbase + wc * 64 + j * 16 + md;
                    if (s < rbv[i][r]) { rbv[i][r] = s; rbi[i][r] = ci; }  // strict <: lowest idx wins
                }
    }

    // Epilogue (once per block): reduce across md lanes, atomicMin global key.
#pragma unroll
    for (int i = 0; i < 4; ++i)
#pragma unroll
        for (int r = 0; r < 4; ++r) {
            float bv = rbv[i][r];
            int bi = rbi[i][r];
#pragma unroll
            for (int m = 1; m < 16; m <<= 1) {
                const float ov = __shfl_xor(bv, m, 64);
                const int oi = __shfl_xor(bi, m, 64);
                if (ov < bv || (ov == bv && oi < bi)) { bv = ov; bi = oi; }
            }
            if (md == 0) {
                unsigned int u = __float_as_uint(bv);
                u = (u & 0x80000000u) ? ~u : (u | 0x80000000u);
                const unsigned long long key = ((unsigned long long)u << 32) | (unsigned int)bi;
                atomicMin(&keys[n0 + wr * 64 + i * 16 + quad * 4 + r], key);
            }
        }
}

// ---------------------------------------------------------------------------
// quantized_st + loss partials + integer code counts
__global__ __launch_bounds__(256) void quant_loss_kernel(const float* __restrict__ x,
                                                         const float* __restrict__ emb,
                                                         const unsigned long long* __restrict__ keys,
                                                         float* __restrict__ out,
                                                         float* __restrict__ partials,
                                                         int* __restrict__ icounts) {
    const int blk = blockIdx.x;
    const int b = blk >> 4;
    const int hw0 = (blk & 15) << 6;
    const int l = threadIdx.x & 63;
    const int cq = threadIdx.x >> 6;
    const int hw = hw0 + l;
    const int n = (b << 10) + hw;
    const int code = (int)(keys[n] & 0xFFFFFFFFull);
    if (threadIdx.x < 64) atomicAdd(&icounts[code], 1);
    const float* erow = emb + (size_t)code * D;
    const float* xb = x + (((size_t)b * 256) << 10) + hw;
    float* ob = out + O_QST + (((size_t)b * 256) << 10) + hw;
    float lsum = 0.f;
#pragma unroll 4
    for (int c = cq; c < D; c += 4) {
        const float xv = xb[(size_t)c << 10];
        const float ev = erow[c];
        ob[(size_t)c << 10] = xv + (ev - xv);
        const float d = xv - ev;
        lsum = fmaf(d, d, lsum);
    }
    __shared__ float sm[4];
    const int lane = threadIdx.x & 63, wv = threadIdx.x >> 6;
#pragma unroll
    for (int off = 32; off; off >>= 1) lsum += __shfl_down(lsum, off, 64);
    if (lane == 0) sm[wv] = lsum;
    __syncthreads();
    if (threadIdx.x == 0) partials[blockIdx.x] = sm[0] + sm[1] + sm[2] + sm[3];
}

// ---------------------------------------------------------------------------
// Exclusive scan of icounts -> basearr; also final loss + perplexity scalars.
__global__ __launch_bounds__(256) void scan_final_kernel(const int* __restrict__ icounts,
                                                         int* __restrict__ basearr,
                                                         const float* __restrict__ partials,
                                                         float* __restrict__ out) {
    const int t = threadIdx.x, lane = t & 63, w = t >> 6;
    int loc = 0;
    float ps = 0.f;
    for (int i = 0; i < 32; ++i) {
        const int c = icounts[t * 32 + i];
        loc += c;
        const float p = (float)c * (1.0f / 16384.0f);
        ps += p * logf(p + 1e-10f);
    }
    // inclusive scan of loc within wave
    int v = loc;
#pragma unroll
    for (int off = 1; off < 64; off <<= 1) {
        const int u = __shfl_up(v, off, 64);
        if (lane >= off) v += u;
    }
    __shared__ int wsum[4];
    __shared__ float fs[8];
    if (lane == 63) wsum[w] = v;
    // reduce loss + perplexity partials
    float lp = partials[t];
#pragma unroll
    for (int off = 32; off; off >>= 1) {
        lp += __shfl_down(lp, off, 64);
        ps += __shfl_down(ps, off, 64);
    }
    if (lane == 0) { fs[w] = lp; fs[4 + w] = ps; }
    __syncthreads();
    int pre = 0;
    for (int i = 0; i < w; ++i) pre += wsum[i];
    int b = pre + v - loc;  // exclusive base for this thread's 32 bins
    for (int i = 0; i < 32; ++i) {
        basearr[t * 32 + i] = b;
        b += icounts[t * 32 + i];
    }
    if (t == 0) {
        out[O_LOSS] = 0.25f * ((fs[0] + fs[1] + fs[2] + fs[3]) / 4194304.0f);
        out[O_PERP] = expf(-(fs[4] + fs[5] + fs[6] + fs[7]));
    }
}

// ---------------------------------------------------------------------------
// Counting-sort slot assignment: rowlist[base[code] + pos] = n
__global__ __launch_bounds__(256) void slot_kernel(const unsigned long long* __restrict__ keys,
                                                   const int* __restrict__ basearr,
                                                   int* __restrict__ cursor,
                                                   int* __restrict__ rowlist) {
    const int n = blockIdx.x * 256 + threadIdx.x;
    const int code = (int)(keys[n] & 0xFFFFFFFFull);
    const int pos = atomicAdd(&cursor[code], 1);
    rowlist[basearr[code] + pos] = n;
}

// ---------------------------------------------------------------------------
// Per-code gather-sum of x rows (replaces atomic scatter) fused with EMA.
// Block k, thread c: s = sum over code-k rows of x[n][c]; coalesced across c.
__global__ __launch_bounds__(256) void gather_ema_kernel(const u16* __restrict__ xhi,
                                                         const u16* __restrict__ xlo,
                                                         const int* __restrict__ icounts,
                                                         const int* __restrict__ basearr,
                                                         const int* __restrict__ rowlist,
                                                         const float* __restrict__ embed_avg,
                                                         const float* __restrict__ cluster_size,
                                                         float* __restrict__ out) {
    const int k = blockIdx.x, c = threadIdx.x;
    const int cnt = icounts[k], b0 = basearr[k];
    float s = 0.f;
    for (int t = 0; t < cnt; ++t) {
        const int n = rowlist[b0 + t];  // wave-uniform
        s += bf2f(xhi[(size_t)n * D + c]) + bf2f(xlo[(size_t)n * D + c]);
    }
    const float ncs = cluster_size[k] * 0.99f + 0.01f * (float)cnt;
    const size_t i = (size_t)k * D + c;
    const float na = embed_avg[i] * 0.99f + 0.01f * s;
    out[O_EAVG + i] = na;
    out[O_EMB + i] = na / fmaxf(ncs, 1e-5f);
    if (c == 0) out[O_CS + k] = ncs;
}

// ---------------------------------------------------------------------------
extern "C" void kernel_launch(void* const* d_in, const int* in_sizes, int n_in,
                              void* d_out, int out_size, void* d_ws, size_t ws_size,
                              hipStream_t stream) {
    const float* x            = (const float*)d_in[0];
    const float* emb          = (const float*)d_in[1];
    const float* cluster_size = (const float*)d_in[2];
    const float* embed_avg    = (const float*)d_in[3];
    float* out = (float*)d_out;
    char* ws = (char*)d_ws;

    float* enorm = (float*)(ws + WS_ENORM);
    unsigned long long* keys = (unsigned long long*)(ws + WS_KEYS);
    int* icounts = (int*)(ws + WS_ICOUNTS);
    int* cursor = (int*)(ws + WS_CURSOR);
    int* basearr = (int*)(ws + WS_BASE);
    int* rowlist = (int*)(ws + WS_ROWLIST);
    float* partials = (float*)(ws + WS_PART);
    u16* xhi = (u16*)(ws + WS_XHI);
    u16* xlo = (u16*)(ws + WS_XLO);
    u16* ehi = (u16*)(ws + WS_EHI);
    u16* elo = (u16*)(ws + WS_ELO);

    hipMemsetAsync(ws + WS_ICOUNTS, 0, 0x10000, stream);           // icounts+cursor
    hipMemsetAsync(ws + WS_KEYS, 0xFF, NROWS * 8, stream);         // argmin keys

    prep_emb_kernel<<<K_CODES, 256, 0, stream>>>(emb, ehi, elo, enorm);
    prep_x_kernel<<<dim3(16, 4, 16), 256, 0, stream>>>(x, xhi, xlo);
    dist_kernel<<<dim3(SLICES, NROWS / BM), 256, 0, stream>>>(xhi, xlo, ehi, elo, enorm, keys);
    quant_loss_kernel<<<256, 256, 0, stream>>>(x, emb, keys, out, partials, icounts);
    scan_final_kernel<<<1, 256, 0, stream>>>(icounts, basearr, partials, out);
    slot_kernel<<<NROWS / 256, 256, 0, stream>>>(keys, basearr, cursor, rowlist);
    gather_ema_kernel<<<K_CODES, 256, 0, stream>>>(xhi, xlo, icounts, basearr, rowlist,
                                                   embed_avg, cluster_size, out);
}

// Round 4
// 298.720 us; speedup vs baseline: 3.7205x; 1.1987x over previous
//
#include <hip/hip_runtime.h>
#include <stdint.h>

// Problem constants
#define K_CODES 8192
#define D 256
#define NROWS 16384      // 16 * 32 * 32
#define NELEM 4194304    // 16 * 256 * 32 * 32

// ws layout (bytes)
#define WS_ENORM   0x00000u                 // 8192 f32 = 32 KB
#define WS_KEYS    0x08000u                 // 16384 u64 = 128 KB
#define WS_ICOUNTS 0x28000u                 // 8192 i32 = 32 KB
#define WS_CURSOR  0x30000u                 // 8192 i32 = 32 KB
#define WS_BASE    0x38000u                 // 8192 i32 = 32 KB
#define WS_ROWLIST 0x40000u                 // 16384 i32 = 64 KB
#define WS_PART    0x50000u                 // 256 f32
#define WS_XHI     0x60000u                 // 16384*256 bf16 = 8 MB
#define WS_XLO     (WS_XHI + 0x800000u)     // 8 MB
#define WS_EHI     (WS_XLO + 0x800000u)     // 4 MB
#define WS_ELO     (WS_EHI + 0x400000u)     // 4 MB

// out offsets (floats), concatenated return order
#define O_QST  0
#define O_LOSS 4194304
#define O_PERP 4194305
#define O_EMB  4194306
#define O_CS   6291458
#define O_EAVG 6299650

typedef unsigned short u16;
typedef __attribute__((ext_vector_type(8))) short bf16x8;
typedef __attribute__((ext_vector_type(4))) float f32x4;

// bf16 round-to-nearest-even split helpers
__device__ __forceinline__ u16 f2bf(float f) {
    uint32_t u = __float_as_uint(f);
    u += 0x7FFFu + ((u >> 16) & 1u);
    return (u16)(u >> 16);
}
__device__ __forceinline__ float bf2f(u16 h) {
    return __uint_as_float(((uint32_t)h) << 16);
}

__device__ __forceinline__ void glds16(const u16* g, u16* lds_base) {
    __builtin_amdgcn_global_load_lds(
        (const __attribute__((address_space(1))) uint32_t*)g,
        (__attribute__((address_space(3))) uint32_t*)lds_base, 16, 0, 0);
}

// ---------------------------------------------------------------------------
// Split emb rows into bf16 hi/lo planes (same [k][c] layout) + row norms.
__global__ __launch_bounds__(256) void prep_emb_kernel(const float* __restrict__ emb,
                                                       u16* __restrict__ eh,
                                                       u16* __restrict__ el,
                                                       float* __restrict__ enorm) {
    const int k = blockIdx.x, t = threadIdx.x;
    const size_t i = (size_t)k * D + t;
    const float v = emb[i];
    const u16 h = f2bf(v);
    const float r = v - bf2f(h);  // exact
    eh[i] = h;
    el[i] = f2bf(r);
    float s = v * v;
#pragma unroll
    for (int off = 32; off; off >>= 1) s += __shfl_down(s, off, 64);
    __shared__ float sm[4];
    if ((t & 63) == 0) sm[t >> 6] = s;
    __syncthreads();
    if (t == 0) enorm[k] = sm[0] + sm[1] + sm[2] + sm[3];
}

// ---------------------------------------------------------------------------
// Split + transpose x: [b][c][hw] f32 -> xhi/xlo [n = b*1024+hw][c] bf16.
__global__ __launch_bounds__(256) void prep_x_kernel(const float* __restrict__ x,
                                                     u16* __restrict__ xhi,
                                                     u16* __restrict__ xlo) {
    __shared__ u16 Lh[64][72];
    __shared__ u16 Ll[64][72];
    const int hw0 = blockIdx.x << 6;
    const int c0 = blockIdx.y << 6;
    const int b = blockIdx.z;
    const int t = threadIdx.x, l = t & 63, w = t >> 6;
#pragma unroll
    for (int i = 0; i < 16; ++i) {
        const int cl = w * 16 + i;
        const float v = x[(((size_t)(b * 256 + c0 + cl)) << 10) + hw0 + l];
        const u16 h = f2bf(v);
        Lh[l][cl] = h;
        Ll[l][cl] = f2bf(v - bf2f(h));
    }
    __syncthreads();
    const int r = t >> 2, cs = t & 3;
    const size_t n = (((size_t)b) << 10) + hw0 + r;
    const size_t o = n * D + c0 + cs * 16;
    *(uint4*)&xhi[o]     = *(const uint4*)&Lh[r][cs * 16];
    *(uint4*)&xhi[o + 8] = *(const uint4*)&Lh[r][cs * 16 + 8];
    *(uint4*)&xlo[o]     = *(const uint4*)&Ll[r][cs * 16];
    *(uint4*)&xlo[o + 8] = *(const uint4*)&Ll[r][cs * 16 + 8];
}

// ---------------------------------------------------------------------------
// Distance GEMM via bf16 hi/lo-split MFMA + fused argmin.
// A-resident design: 256 blocks (2 slices x 128 row-blocks) = 1 block/CU.
// Per block: stage A (128 rows x 256 k x hi/lo = 128 KB) into LDS ONCE
// (XOR-swizzled: slot = kchunk ^ (row&31), so 512B-row-stride frag reads are
// conflict-free), then loop 32 code-tiles x 8 k-tiles staging only B
// (16 KB/kt, hi/lo interleaved per code row in 128B, slot = g ^ (code&7)),
// DOUBLE-BUFFERED: stage(m+1) issued right after the barrier -> the barrier's
// vmcnt(0) drain waits on loads issued a full compute iteration earlier.
// Dynamic LDS = 64K(Ah) + 64K(Al) + 2x16K(B) = 160 KB (1 block/CU by design).
#define BM 128
#define BN 128
#define SLICES 2
#define CT_PER 32

__global__ __launch_bounds__(256, 1) void dist_kernel(const u16* __restrict__ xhi,
                                                      const u16* __restrict__ xlo,
                                                      const u16* __restrict__ ehi,
                                                      const u16* __restrict__ elo,
                                                      const float* __restrict__ enorm,
                                                      unsigned long long* __restrict__ keys) {
    extern __shared__ __align__(16) u16 lds[];   // [0,32768)=Ah [32768,65536)=Al [65536,81920)=B dbuf

    const int tid = threadIdx.x;
    const int l = tid & 63, w = tid >> 6;
    const int wr = w >> 1, wc = w & 1;       // wave's 64x64 quadrant
    const int slice = blockIdx.x;            // 0..1
    const int n0 = blockIdx.y * BM;          // row block
    const int md = l & 15, quad = l >> 4;

    // ---- stage A once: window win (1KB) covers rows 2win..2win+1 ----------
    // lane l -> row rA = 2win + (l>>5), slot s = l&31, global chunk g = s ^ (rA&31)
#pragma unroll
    for (int wd = 0; wd < 16; ++wd) {
        const int win = w * 16 + wd;
        const int rA = 2 * win + (l >> 5);
        const int g = (l & 31) ^ (rA & 31);
        const size_t src = (size_t)(n0 + rA) * D + g * 8;
        glds16(xhi + src, &lds[win * 512]);
        glds16(xlo + src, &lds[32768 + win * 512]);
    }

    // ---- B staging per-lane source base (w8 windows of 8 code rows) -------
    // lane l: rloc=l>>3, s=l&7, g=s^rloc; g<4 -> ehi chunk g, else elo chunk g-4
    const int rloc = l >> 3, sB = l & 7, gB = sB ^ rloc;
    const u16* PB[4];
#pragma unroll
    for (int w8 = 0; w8 < 4; ++w8) {
        const u16* pl = (gB & 4) ? elo : ehi;
        PB[w8] = pl + (size_t)(slice * 4096 + w * 32 + w8 * 8 + rloc) * D + (gB & 3) * 8;
    }
    const int bdst = 65536 + (w * 32) * 64;  // wave-uniform LDS dest (u16 idx), +w8*512, +buf*8192

    // stage B for m=0 (ct=0, kt=0) into buf 0
#pragma unroll
    for (int w8 = 0; w8 < 4; ++w8) glds16(PB[w8], &lds[bdst + w8 * 512]);

    // ---- frag-read address constants --------------------------------------
    int rbase[4], rh[4];                     // A frags: row rA = wr*64+i*16+md
#pragma unroll
    for (int i = 0; i < 4; ++i) {
        const int rA = wr * 64 + i * 16 + md;
        rbase[i] = rA * 256;
        rh[i] = rA & 31;
    }
    int offBH[4], offBL[4];                  // B frags: code cr = wc*64+j*16+md
#pragma unroll
    for (int j = 0; j < 4; ++j) {
        const int cr = wc * 64 + j * 16 + md;
        offBH[j] = 65536 + cr * 64 + ((quad) ^ (md & 7)) * 8;
        offBL[j] = 65536 + cr * 64 + ((quad + 4) ^ (md & 7)) * 8;
    }

    float rbv[4][4];
    int rbi[4][4];
#pragma unroll
    for (int i = 0; i < 4; ++i)
#pragma unroll
        for (int r = 0; r < 4; ++r) { rbv[i][r] = 1e30f; rbi[i][r] = 0; }

    for (int ct = 0; ct < CT_PER; ++ct) {
        f32x4 acc[4][4];
#pragma unroll
        for (int i = 0; i < 4; ++i)
#pragma unroll
            for (int j = 0; j < 4; ++j) acc[i][j] = (f32x4)0.f;

#pragma unroll
        for (int kt = 0; kt < 8; ++kt) {
            __syncthreads();
            const int m = ct * 8 + kt;
            if (m < CT_PER * 8 - 1) {
                // stage (m+1) into buf (m+1)&1
                const int m1 = m + 1;
                const int soff = (m1 >> 3) * 32768 + (m1 & 7) * 32;  // ct2*128*256 + kt2*32
                const int db = bdst + ((m1 & 1) << 13);
#pragma unroll
                for (int w8 = 0; w8 < 4; ++w8)
                    glds16(PB[w8] + soff, &lds[db + w8 * 512]);
            }

            const int bufo = (kt & 1) << 13;     // reading buf = m&1 = kt&1
            bf16x8 ah[4], al4[4], bh4[4], bl4[4];
#pragma unroll
            for (int i = 0; i < 4; ++i) {
                const int slot = ((kt << 2) | quad) ^ rh[i];
                ah[i]  = *(const bf16x8*)&lds[rbase[i] + slot * 8];
                al4[i] = *(const bf16x8*)&lds[32768 + rbase[i] + slot * 8];
            }
#pragma unroll
            for (int j = 0; j < 4; ++j) {
                bh4[j] = *(const bf16x8*)&lds[bufo + offBH[j]];
                bl4[j] = *(const bf16x8*)&lds[bufo + offBL[j]];
            }
#pragma unroll
            for (int i = 0; i < 4; ++i)
#pragma unroll
                for (int j = 0; j < 4; ++j) {
                    acc[i][j] = __builtin_amdgcn_mfma_f32_16x16x32_bf16(ah[i],  bh4[j], acc[i][j], 0, 0, 0);
                    acc[i][j] = __builtin_amdgcn_mfma_f32_16x16x32_bf16(ah[i],  bl4[j], acc[i][j], 0, 0, 0);
                    acc[i][j] = __builtin_amdgcn_mfma_f32_16x16x32_bf16(al4[i], bh4[j], acc[i][j], 0, 0, 0);
                }
        }

        // merge this ct's 128 codes into per-lane running best
        const int gc0 = slice * 4096 + ct * 128;
        float ec[4];
#pragma unroll
        for (int j = 0; j < 4; ++j) ec[j] = enorm[gc0 + wc * 64 + j * 16 + md];
#pragma unroll
        for (int i = 0; i < 4; ++i)
#pragma unroll
            for (int r = 0; r < 4; ++r)
#pragma unroll
                for (int j = 0; j < 4; ++j) {
                    const float s = fmaf(-2.f, acc[i][j][r], ec[j]);
                    const int ci = gc0 + wc * 64 + j * 16 + md;
                    if (s < rbv[i][r]) { rbv[i][r] = s; rbi[i][r] = ci; }  // strict <: lowest idx wins
                }
    }

    // Epilogue (once per block): reduce across md lanes, atomicMin global key.
#pragma unroll
    for (int i = 0; i < 4; ++i)
#pragma unroll
        for (int r = 0; r < 4; ++r) {
            float bv = rbv[i][r];
            int bi = rbi[i][r];
#pragma unroll
            for (int m = 1; m < 16; m <<= 1) {
                const float ov = __shfl_xor(bv, m, 64);
                const int oi = __shfl_xor(bi, m, 64);
                if (ov < bv || (ov == bv && oi < bi)) { bv = ov; bi = oi; }
            }
            if (md == 0) {
                unsigned int u = __float_as_uint(bv);
                u = (u & 0x80000000u) ? ~u : (u | 0x80000000u);
                const unsigned long long key = ((unsigned long long)u << 32) | (unsigned int)bi;
                atomicMin(&keys[n0 + wr * 64 + i * 16 + quad * 4 + r], key);
            }
        }
}

// ---------------------------------------------------------------------------
// quantized_st + loss partials + integer code counts
__global__ __launch_bounds__(256) void quant_loss_kernel(const float* __restrict__ x,
                                                         const float* __restrict__ emb,
                                                         const unsigned long long* __restrict__ keys,
                                                         float* __restrict__ out,
                                                         float* __restrict__ partials,
                                                         int* __restrict__ icounts) {
    const int blk = blockIdx.x;
    const int b = blk >> 4;
    const int hw0 = (blk & 15) << 6;
    const int l = threadIdx.x & 63;
    const int cq = threadIdx.x >> 6;
    const int hw = hw0 + l;
    const int n = (b << 10) + hw;
    const int code = (int)(keys[n] & 0xFFFFFFFFull);
    if (threadIdx.x < 64) atomicAdd(&icounts[code], 1);
    const float* erow = emb + (size_t)code * D;
    const float* xb = x + (((size_t)b * 256) << 10) + hw;
    float* ob = out + O_QST + (((size_t)b * 256) << 10) + hw;
    float lsum = 0.f;
#pragma unroll 4
    for (int c = cq; c < D; c += 4) {
        const float xv = xb[(size_t)c << 10];
        const float ev = erow[c];
        ob[(size_t)c << 10] = xv + (ev - xv);
        const float d = xv - ev;
        lsum = fmaf(d, d, lsum);
    }
    __shared__ float sm[4];
    const int lane = threadIdx.x & 63, wv = threadIdx.x >> 6;
#pragma unroll
    for (int off = 32; off; off >>= 1) lsum += __shfl_down(lsum, off, 64);
    if (lane == 0) sm[wv] = lsum;
    __syncthreads();
    if (threadIdx.x == 0) partials[blockIdx.x] = sm[0] + sm[1] + sm[2] + sm[3];
}

// ---------------------------------------------------------------------------
// Exclusive scan of icounts -> basearr; also final loss + perplexity scalars.
__global__ __launch_bounds__(256) void scan_final_kernel(const int* __restrict__ icounts,
                                                         int* __restrict__ basearr,
                                                         const float* __restrict__ partials,
                                                         float* __restrict__ out) {
    const int t = threadIdx.x, lane = t & 63, w = t >> 6;
    int loc = 0;
    float ps = 0.f;
    for (int i = 0; i < 32; ++i) {
        const int c = icounts[t * 32 + i];
        loc += c;
        const float p = (float)c * (1.0f / 16384.0f);
        ps += p * logf(p + 1e-10f);
    }
    // inclusive scan of loc within wave
    int v = loc;
#pragma unroll
    for (int off = 1; off < 64; off <<= 1) {
        const int u = __shfl_up(v, off, 64);
        if (lane >= off) v += u;
    }
    __shared__ int wsum[4];
    __shared__ float fs[8];
    if (lane == 63) wsum[w] = v;
    // reduce loss + perplexity partials
    float lp = partials[t];
#pragma unroll
    for (int off = 32; off; off >>= 1) {
        lp += __shfl_down(lp, off, 64);
        ps += __shfl_down(ps, off, 64);
    }
    if (lane == 0) { fs[w] = lp; fs[4 + w] = ps; }
    __syncthreads();
    int pre = 0;
    for (int i = 0; i < w; ++i) pre += wsum[i];
    int b = pre + v - loc;  // exclusive base for this thread's 32 bins
    for (int i = 0; i < 32; ++i) {
        basearr[t * 32 + i] = b;
        b += icounts[t * 32 + i];
    }
    if (t == 0) {
        out[O_LOSS] = 0.25f * ((fs[0] + fs[1] + fs[2] + fs[3]) / 4194304.0f);
        out[O_PERP] = expf(-(fs[4] + fs[5] + fs[6] + fs[7]));
    }
}

// ---------------------------------------------------------------------------
// Counting-sort slot assignment: rowlist[base[code] + pos] = n
__global__ __launch_bounds__(256) void slot_kernel(const unsigned long long* __restrict__ keys,
                                                   const int* __restrict__ basearr,
                                                   int* __restrict__ cursor,
                                                   int* __restrict__ rowlist) {
    const int n = blockIdx.x * 256 + threadIdx.x;
    const int code = (int)(keys[n] & 0xFFFFFFFFull);
    const int pos = atomicAdd(&cursor[code], 1);
    rowlist[basearr[code] + pos] = n;
}

// ---------------------------------------------------------------------------
// Per-code gather-sum of x rows (replaces atomic scatter) fused with EMA.
__global__ __launch_bounds__(256) void gather_ema_kernel(const u16* __restrict__ xhi,
                                                         const u16* __restrict__ xlo,
                                                         const int* __restrict__ icounts,
                                                         const int* __restrict__ basearr,
                                                         const int* __restrict__ rowlist,
                                                         const float* __restrict__ embed_avg,
                                                         const float* __restrict__ cluster_size,
                                                         float* __restrict__ out) {
    const int k = blockIdx.x, c = threadIdx.x;
    const int cnt = icounts[k], b0 = basearr[k];
    float s = 0.f;
    for (int t = 0; t < cnt; ++t) {
        const int n = rowlist[b0 + t];  // wave-uniform
        s += bf2f(xhi[(size_t)n * D + c]) + bf2f(xlo[(size_t)n * D + c]);
    }
    const float ncs = cluster_size[k] * 0.99f + 0.01f * (float)cnt;
    const size_t i = (size_t)k * D + c;
    const float na = embed_avg[i] * 0.99f + 0.01f * s;
    out[O_EAVG + i] = na;
    out[O_EMB + i] = na / fmaxf(ncs, 1e-5f);
    if (c == 0) out[O_CS + k] = ncs;
}

// ---------------------------------------------------------------------------
extern "C" void kernel_launch(void* const* d_in, const int* in_sizes, int n_in,
                              void* d_out, int out_size, void* d_ws, size_t ws_size,
                              hipStream_t stream) {
    const float* x            = (const float*)d_in[0];
    const float* emb          = (const float*)d_in[1];
    const float* cluster_size = (const float*)d_in[2];
    const float* embed_avg    = (const float*)d_in[3];
    float* out = (float*)d_out;
    char* ws = (char*)d_ws;

    float* enorm = (float*)(ws + WS_ENORM);
    unsigned long long* keys = (unsigned long long*)(ws + WS_KEYS);
    int* icounts = (int*)(ws + WS_ICOUNTS);
    int* cursor = (int*)(ws + WS_CURSOR);
    int* basearr = (int*)(ws + WS_BASE);
    int* rowlist = (int*)(ws + WS_ROWLIST);
    float* partials = (float*)(ws + WS_PART);
    u16* xhi = (u16*)(ws + WS_XHI);
    u16* xlo = (u16*)(ws + WS_XLO);
    u16* ehi = (u16*)(ws + WS_EHI);
    u16* elo = (u16*)(ws + WS_ELO);

    static int lds_attr_set = 0;
    if (!lds_attr_set) {
        hipFuncSetAttribute((const void*)dist_kernel,
                            hipFuncAttributeMaxDynamicSharedMemorySize, 163840);
        lds_attr_set = 1;
    }

    hipMemsetAsync(ws + WS_ICOUNTS, 0, 0x10000, stream);           // icounts+cursor
    hipMemsetAsync(ws + WS_KEYS, 0xFF, NROWS * 8, stream);         // argmin keys

    prep_emb_kernel<<<K_CODES, 256, 0, stream>>>(emb, ehi, elo, enorm);
    prep_x_kernel<<<dim3(16, 4, 16), 256, 0, stream>>>(x, xhi, xlo);
    dist_kernel<<<dim3(SLICES, NROWS / BM), 256, 163840, stream>>>(xhi, xlo, ehi, elo, enorm, keys);
    quant_loss_kernel<<<256, 256, 0, stream>>>(x, emb, keys, out, partials, icounts);
    scan_final_kernel<<<1, 256, 0, stream>>>(icounts, basearr, partials, out);
    slot_kernel<<<NROWS / 256, 256, 0, stream>>>(keys, basearr, cursor, rowlist);
    gather_ema_kernel<<<K_CODES, 256, 0, stream>>>(xhi, xlo, icounts, basearr, rowlist,
                                                   embed_avg, cluster_size, out);
}